// Round 6
// baseline (249.961 us; speedup 1.0000x reference)
//
#include <hip/hip_runtime.h>

// Self-attention, B=4 S=2048 D=1024 H=16 Hd=64, fp32 in/out, bf16 MFMA inside.
// cvt -> GEMM QKV (256^2 tile, counted-vmcnt pipeline, T2 swizzle, Q*0.125*log2e)
// -> flash attn (32x32 MFMA, in-reg P, swizzled LDS, defer-max) -> GEMM out+bias.

typedef unsigned short u16;
typedef unsigned int u32;
typedef float f32x4 __attribute__((ext_vector_type(4)));
typedef float f32x16 __attribute__((ext_vector_type(16)));
typedef short s16x8 __attribute__((ext_vector_type(8)));

#define DEVI __device__ __forceinline__

DEVI u16 f32_bf16(float f) {
  unsigned u = __float_as_uint(f);
  return (u16)((u + 0x7FFFu + ((u >> 16) & 1u)) >> 16);
}

DEVI u32 pack_pk(float a, float b) {
  u32 r;
  asm("v_cvt_pk_bf16_f32 %0, %1, %2" : "=v"(r) : "v"(a), "v"(b));
  return r;
}

DEVI void gload_lds16(const void* g, void* l) {
  __builtin_amdgcn_global_load_lds((const __attribute__((address_space(1))) void*)g,
                                   (__attribute__((address_space(3))) void*)l, 16, 0, 0);
}

#if __has_builtin(__builtin_amdgcn_permlane32_swap)
typedef int i32x2 __attribute__((ext_vector_type(2)));
DEVI void plswap(u32& a, u32& b, int hi) {
  i32x2 r = __builtin_amdgcn_permlane32_swap((int)a, (int)b, false, false);
  a = (u32)r[0];
  b = (u32)r[1];
}
#else
DEVI void plswap(u32& a, u32& b, int hi) {
  u32 ta = (u32)__shfl_xor((int)a, 32);
  u32 tb = (u32)__shfl_xor((int)b, 32);
  u32 na = hi ? tb : a;
  u32 nb = hi ? b : ta;
  a = na;
  b = nb;
}
#endif

// ---------------- fp32 -> bf16 conversions ----------------
__global__ void cvt_kernel(const float* __restrict__ in, u16* __restrict__ out, int n4) {
  int i = blockIdx.x * 256 + threadIdx.x;
  if (i >= n4) return;
  float4 v = ((const float4*)in)[i];
  ushort4 o;
  o.x = f32_bf16(v.x); o.y = f32_bf16(v.y);
  o.z = f32_bf16(v.z); o.w = f32_bf16(v.w);
  ((ushort4*)out)[i] = o;
}

__global__ void cvt_w_kernel(const float* __restrict__ wq, const float* __restrict__ wk,
                             const float* __restrict__ wv, const float* __restrict__ wo,
                             u16* __restrict__ wcat, u16* __restrict__ wo_bf) {
  int i = blockIdx.x * 256 + threadIdx.x;
  int m = blockIdx.y;
  const float* src = (m == 0) ? wq : (m == 1) ? wk : (m == 2) ? wv : wo;
  u16* dst = (m < 3) ? (wcat + m * 1048576) : wo_bf;
  float4 v = ((const float4*)src)[i];
  ushort4 o;
  o.x = f32_bf16(v.x); o.y = f32_bf16(v.y);
  o.z = f32_bf16(v.z); o.w = f32_bf16(v.w);
  ((ushort4*)dst)[i] = o;
}

// ---------------- 256^2 B^T GEMM: C[M,N] = A[M,K] * B[N,K]^T ----------------
// 512 thr = 8 waves (2M x 4N); wave tile 128x64; BK=64; LDS 128 KiB dbuf.
// Staging: 8 global_load_lds/tile (units of 64 rows x 128B), pre-swizzled source,
// order [B0,B1,B2,B3,A0,A2,A1,A3]; waits vmcnt(2)@ph0, vmcnt(4)@ph2 (counted, T4).
// Phase q computes C-quadrant m-frags {2q,2q+1} x 4 n-frags x K=64 (16 MFMA, T5 prio).
// MODE 0: bf16 out, cols<1024 scaled by 0.125*log2e. MODE 1: fp32 out + bias.
template <int MODE>
__global__ __launch_bounds__(512, 2) void gemm256(
    const u16* __restrict__ A, const u16* __restrict__ B, void* __restrict__ Cout,
    const float* __restrict__ bias, int M, int N, int K) {
  __shared__ u16 SA[2][256 * 64];
  __shared__ u16 SB[2][256 * 64];
  const int tid = threadIdx.x;
  const int lane = tid & 63, w = tid >> 6;
  const int wm = w >> 2, wn = w & 3;
  const int l15 = lane & 15, l4 = lane >> 4;
  const int swz = (l15 & 7) << 3;  // elem-index XOR for frag reads

  // XCD swizzle (nwg % 8 == 0 at both call sites)
  const int gx = gridDim.x;
  const int nwg = gx * gridDim.y;
  int ib = blockIdx.y * gx + blockIdx.x;
  int t = (ib & 7) * (nwg >> 3) + (ib >> 3);
  const int m0 = (t / gx) * 256, n0 = (t % gx) * 256;

  // staging: unit = 64 rows x 64 elems (8KB); wave w covers bytes [w*1024, +1024)
  // linear LDS dest byte = lane*16 -> row = w*8 + (lane>>3), slot' = lane&7;
  // global slot = slot' ^ (row&7)  (pre-swizzled source, rule #21)
  const int srow = w * 8 + (lane >> 3);
  const int scol = ((lane & 7) ^ (lane >> 3)) * 8;

  const u16* Ab = A + (size_t)m0 * K;
  const u16* Bb = B + (size_t)n0 * K;

  f32x4 acc[8][4] = {};

  // prologue: stage tile 0 -> buf 0
  gload_lds16(Bb + (size_t)(0 * 64 + srow) * K + scol, &SB[0][0 * 4096 + w * 512]);
  gload_lds16(Bb + (size_t)(1 * 64 + srow) * K + scol, &SB[0][1 * 4096 + w * 512]);
  gload_lds16(Bb + (size_t)(2 * 64 + srow) * K + scol, &SB[0][2 * 4096 + w * 512]);
  gload_lds16(Bb + (size_t)(3 * 64 + srow) * K + scol, &SB[0][3 * 4096 + w * 512]);
  gload_lds16(Ab + (size_t)(0 * 64 + srow) * K + scol, &SA[0][0 * 4096 + w * 512]);
  gload_lds16(Ab + (size_t)(2 * 64 + srow) * K + scol, &SA[0][2 * 4096 + w * 512]);
  gload_lds16(Ab + (size_t)(1 * 64 + srow) * K + scol, &SA[0][1 * 4096 + w * 512]);
  gload_lds16(Ab + (size_t)(3 * 64 + srow) * K + scol, &SA[0][3 * 4096 + w * 512]);

  const int NT = K >> 6;
  for (int tt = 0; tt < NT; ++tt) {
    const int p = tt & 1;
    const u16* sa = &SA[p][0];
    const u16* sb = &SB[p][0];
    u16* na = &SA[p ^ 1][0];
    u16* nb = &SB[p ^ 1][0];
    const int kn = (tt + 1) << 6;
    const bool more = (tt + 1) < NT;

    s16x8 bf[4][2];
#pragma unroll
    for (int q = 0; q < 4; ++q) {
      if (q == 0) {
        // tile tt loads 1-6 (B all + A0,A2) done; A1,A3 still in flight
        asm volatile("s_waitcnt vmcnt(2)" ::: "memory");
        __builtin_amdgcn_s_barrier();
        __builtin_amdgcn_sched_barrier(0);
        if (more) {
          gload_lds16(Bb + (size_t)(0 * 64 + srow) * K + kn + scol, &nb[0 * 4096 + w * 512]);
          gload_lds16(Bb + (size_t)(1 * 64 + srow) * K + kn + scol, &nb[1 * 4096 + w * 512]);
        }
#pragma unroll
        for (int nf = 0; nf < 4; ++nf)
#pragma unroll
          for (int ks = 0; ks < 2; ++ks)
            bf[nf][ks] = *(const s16x8*)&sb[(wn * 64 + nf * 16 + l15) * 64 +
                                            ((ks * 32 + l4 * 8) ^ swz)];
      } else if (q == 1) {
        if (more) {
          gload_lds16(Bb + (size_t)(2 * 64 + srow) * K + kn + scol, &nb[2 * 4096 + w * 512]);
          gload_lds16(Bb + (size_t)(3 * 64 + srow) * K + kn + scol, &nb[3 * 4096 + w * 512]);
        }
      } else if (q == 2) {
        // need A1,A3 of tile tt; leave the 4 B' loads of tile tt+1 in flight
        if (more) {
          asm volatile("s_waitcnt vmcnt(4)" ::: "memory");
        } else {
          asm volatile("s_waitcnt vmcnt(0)" ::: "memory");
        }
        __builtin_amdgcn_s_barrier();
        __builtin_amdgcn_sched_barrier(0);
        if (more) {
          gload_lds16(Ab + (size_t)(0 * 64 + srow) * K + kn + scol, &na[0 * 4096 + w * 512]);
          gload_lds16(Ab + (size_t)(2 * 64 + srow) * K + kn + scol, &na[2 * 4096 + w * 512]);
        }
      } else {
        if (more) {
          gload_lds16(Ab + (size_t)(1 * 64 + srow) * K + kn + scol, &na[1 * 4096 + w * 512]);
          gload_lds16(Ab + (size_t)(3 * 64 + srow) * K + kn + scol, &na[3 * 4096 + w * 512]);
        }
      }

      s16x8 af[2][2];
#pragma unroll
      for (int m2 = 0; m2 < 2; ++m2)
#pragma unroll
        for (int ks = 0; ks < 2; ++ks)
          af[m2][ks] = *(const s16x8*)&sa[(wm * 128 + (q * 2 + m2) * 16 + l15) * 64 +
                                          ((ks * 32 + l4 * 8) ^ swz)];
      __builtin_amdgcn_s_setprio(1);
#pragma unroll
      for (int m2 = 0; m2 < 2; ++m2)
#pragma unroll
        for (int nf = 0; nf < 4; ++nf)
#pragma unroll
          for (int ks = 0; ks < 2; ++ks)
            acc[q * 2 + m2][nf] = __builtin_amdgcn_mfma_f32_16x16x32_bf16(
                af[m2][ks], bf[nf][ks], acc[q * 2 + m2][nf], 0, 0, 0);
      __builtin_amdgcn_s_setprio(0);
    }
  }

  // epilogue: C/D layout col=lane&15, row=(lane>>4)*4+reg
#pragma unroll
  for (int mf = 0; mf < 8; ++mf) {
    int row = m0 + wm * 128 + mf * 16 + l4 * 4;
#pragma unroll
    for (int nf = 0; nf < 4; ++nf) {
      int col = n0 + wn * 64 + nf * 16 + l15;
      if (MODE == 0) {
        u16* C = (u16*)Cout;
        float scale = (col < 1024) ? 0.18033688f : 1.0f;  // 0.125 * log2(e)
#pragma unroll
        for (int j = 0; j < 4; ++j)
          C[(size_t)(row + j) * N + col] = f32_bf16(acc[mf][nf][j] * scale);
      } else {
        float* C = (float*)Cout;
        float bb = bias[col];
#pragma unroll
        for (int j = 0; j < 4; ++j)
          C[(size_t)(row + j) * N + col] = acc[mf][nf][j] + bb;
      }
    }
  }
}

// ---------------- flash attention, 32x32 MFMA (unchanged from round 5) ----------------
__global__ __launch_bounds__(256, 2) void attn_kernel(const u16* __restrict__ QKV,
                                                      u16* __restrict__ AO) {
  __shared__ u16 Ks[2][64 * 64];  // [key][d], byte ^= (key&7)<<4
  __shared__ u16 Vt[2][64 * 64];  // [d][key], byte ^= (d&7)<<4
  const int tid = threadIdx.x;
  const int lane = tid & 63, w = tid >> 6;
  const int l31 = lane & 31, hi = lane >> 5;

  int ib = blockIdx.z * 256 + blockIdx.y * 16 + blockIdx.x;
  int tb = (ib & 7) * 128 + (ib >> 3);
  const int h = (tb >> 4) & 15, b = tb >> 8;
  const int rowbase = b * 2048;
  const int q0 = (tb & 15) * 128 + w * 32;

  s16x8 qa[4];
  {
    const u16* qp = QKV + (size_t)(rowbase + q0 + l31) * 3072 + h * 64 + hi * 8;
#pragma unroll
    for (int s = 0; s < 4; ++s) qa[s] = *(const s16x8*)(qp + s * 16);
  }

  const char* kbase = (const char*)(QKV + (size_t)rowbase * 3072 + 1024 + h * 64);
  const u16* vbase = QKV + (size_t)rowbase * 3072 + 2048 + h * 64;

  const int kgrow = lane >> 3;
  const int kgcol = ((lane & 7) * 16) ^ ((lane >> 3) << 4);
  const int kv = (tid & 31) * 2;
  const int dv = (tid >> 5) * 8;

  f32x16 o0 = {}, o1 = {};
  float mrow = -1e30f, lrow = 0.f;

  {
#pragma unroll
    for (int c = 0; c < 2; ++c) {
      int chunk = w * 2 + c;
      gload_lds16(kbase + (chunk * 8 + kgrow) * 6144 + kgcol, &Ks[0][chunk * 512]);
    }
    const u16* vp = vbase + kv * 3072 + dv;
    s16x8 v0 = *(const s16x8*)vp, v1 = *(const s16x8*)(vp + 3072);
#pragma unroll
    for (int i = 0; i < 8; ++i) {
      int d = dv + i;
      *(u32*)((char*)&Vt[0][0] + d * 128 + ((kv * 2) ^ ((d & 7) << 4))) =
          (u32)(u16)v0[i] | ((u32)(u16)v1[i] << 16);
    }
  }
  __syncthreads();

  for (int kt = 0; kt < 32; ++kt) {
    const int cur = kt & 1;
    s16x8 v0, v1;
    if (kt < 31) {
      const char* kb = kbase + (size_t)(kt + 1) * 64 * 6144;
#pragma unroll
      for (int c = 0; c < 2; ++c) {
        int chunk = w * 2 + c;
        gload_lds16(kb + (chunk * 8 + kgrow) * 6144 + kgcol, &Ks[cur ^ 1][chunk * 512]);
      }
      const u16* vp = vbase + ((kt + 1) * 64 + kv) * 3072 + dv;
      v0 = *(const s16x8*)vp;
      v1 = *(const s16x8*)(vp + 3072);
    }

    const char* Kb = (const char*)&Ks[cur][0];
    const char* Vb = (const char*)&Vt[cur][0];

    f32x16 sacc[2];
#pragma unroll
    for (int step = 0; step < 2; ++step) {
      const int keyrow = step * 32 + l31;
      const int swzk = (keyrow & 7) << 4;
      f32x16 t = {};
      __builtin_amdgcn_s_setprio(1);
#pragma unroll
      for (int s = 0; s < 4; ++s) {
        s16x8 kf = *(const s16x8*)(Kb + keyrow * 128 + ((s * 32 + hi * 16) ^ swzk));
        t = __builtin_amdgcn_mfma_f32_32x32x16_bf16(kf, qa[s], t, 0, 0, 0);
      }
      __builtin_amdgcn_s_setprio(0);
      sacc[step] = t;
    }

#pragma unroll
    for (int step = 0; step < 2; ++step) {
      f32x16 s_acc = sacc[step];
      float mx[8];
#pragma unroll
      for (int r = 0; r < 8; ++r) mx[r] = fmaxf(s_acc[r], s_acc[r + 8]);
#pragma unroll
      for (int r = 0; r < 4; ++r) mx[r] = fmaxf(mx[r], mx[r + 4]);
      float m4 = fmaxf(fmaxf(mx[0], mx[1]), fmaxf(mx[2], mx[3]));
      m4 = fmaxf(m4, __shfl_xor(m4, 32));
      if (!__all(m4 <= mrow + 8.f)) {  // defer-max (T13)
        float mnew = fmaxf(mrow, m4);
        float corr = __builtin_amdgcn_exp2f(mrow - mnew);
        lrow *= corr;
#pragma unroll
        for (int r = 0; r < 16; ++r) { o0[r] *= corr; o1[r] *= corr; }
        mrow = mnew;
      }
      float p[16];
#pragma unroll
      for (int r = 0; r < 16; ++r) p[r] = __builtin_amdgcn_exp2f(s_acc[r] - mrow);
      float sm[8];
#pragma unroll
      for (int r = 0; r < 8; ++r) sm[r] = p[r] + p[r + 8];
#pragma unroll
      for (int r = 0; r < 4; ++r) sm[r] += sm[r + 4];
      float rs = (sm[0] + sm[1]) + (sm[2] + sm[3]);
      rs += __shfl_xor(rs, 32);
      lrow += rs;

      u32 pk[8];
#pragma unroll
      for (int j = 0; j < 8; ++j) pk[j] = pack_pk(p[2 * j], p[2 * j + 1]);
      plswap(pk[0], pk[2], hi);
      plswap(pk[1], pk[3], hi);
      plswap(pk[4], pk[6], hi);
      plswap(pk[5], pk[7], hi);
      union { u32 u[4]; s16x8 v; } pb0, pb1;
      pb0.u[0] = pk[0]; pb0.u[1] = pk[1]; pb0.u[2] = pk[2]; pb0.u[3] = pk[3];
      pb1.u[0] = pk[4]; pb1.u[1] = pk[5]; pb1.u[2] = pk[6]; pb1.u[3] = pk[7];

      const int swzv = (l31 & 7) << 4;
      __builtin_amdgcn_s_setprio(1);
#pragma unroll
      for (int ks = 0; ks < 2; ++ks) {
        int cbyte = (step * 64 + ks * 32 + hi * 16) ^ swzv;
        s16x8 vf0 = *(const s16x8*)(Vb + l31 * 128 + cbyte);
        s16x8 vf1 = *(const s16x8*)(Vb + (32 + l31) * 128 + cbyte);
        s16x8 pf = ks ? pb1.v : pb0.v;
        o0 = __builtin_amdgcn_mfma_f32_32x32x16_bf16(vf0, pf, o0, 0, 0, 0);
        o1 = __builtin_amdgcn_mfma_f32_32x32x16_bf16(vf1, pf, o1, 0, 0, 0);
      }
      __builtin_amdgcn_s_setprio(0);
    }

    if (kt < 31) {
#pragma unroll
      for (int i = 0; i < 8; ++i) {
        int d = dv + i;
        *(u32*)((char*)&Vt[cur ^ 1][0] + d * 128 + ((kv * 2) ^ ((d & 7) << 4))) =
            (u32)(u16)v0[i] | ((u32)(u16)v1[i] << 16);
      }
    }
    __syncthreads();
  }

  float inv = __builtin_amdgcn_rcpf(lrow);
  u16* op = AO + (size_t)(rowbase + q0 + l31) * 1024 + h * 64;
#pragma unroll
  for (int g = 0; g < 4; ++g) {
    ushort4 s0, s1;
    s0.x = f32_bf16(o0[g * 4 + 0] * inv);
    s0.y = f32_bf16(o0[g * 4 + 1] * inv);
    s0.z = f32_bf16(o0[g * 4 + 2] * inv);
    s0.w = f32_bf16(o0[g * 4 + 3] * inv);
    s1.x = f32_bf16(o1[g * 4 + 0] * inv);
    s1.y = f32_bf16(o1[g * 4 + 1] * inv);
    s1.z = f32_bf16(o1[g * 4 + 2] * inv);
    s1.w = f32_bf16(o1[g * 4 + 3] * inv);
    *(ushort4*)(op + g * 8 + 4 * hi) = s0;
    *(ushort4*)(op + 32 + g * 8 + 4 * hi) = s1;
  }
}

// ---------------- launch ----------------
extern "C" void kernel_launch(void* const* d_in, const int* in_sizes, int n_in,
                              void* d_out, int out_size, void* d_ws, size_t ws_size,
                              hipStream_t stream) {
  const float* x = (const float*)d_in[0];
  const float* Wq = (const float*)d_in[1];
  const float* Wk = (const float*)d_in[2];
  const float* Wv = (const float*)d_in[3];
  const float* Wo = (const float*)d_in[4];
  const float* bo = (const float*)d_in[5];
  float* out = (float*)d_out;

  char* ws = (char*)d_ws;
  u16* x_bf = (u16*)ws;                                   // 16.8 MB
  u16* Wcat = (u16*)(ws + 16777216);                      //  6.3 MB
  u16* Wo_bf = (u16*)(ws + 16777216 + 6291456);           //  2.1 MB
  u16* QKV = (u16*)(ws + 16777216 + 6291456 + 2097152);   // 50.3 MB
  u16* AO = (u16*)(ws + 16777216 + 6291456 + 2097152 + 50331648);  // 16.8 MB

  cvt_kernel<<<8192, 256, 0, stream>>>(x, x_bf, 8192 * 1024 / 4);
  cvt_w_kernel<<<dim3(1024, 4), 256, 0, stream>>>(Wq, Wk, Wv, Wo, Wcat, Wo_bf);

  // QKV = x_bf @ Wcat^T : M=8192, N=3072 -> grid 12x32 = 384 blocks (%8==0)
  gemm256<0><<<dim3(12, 32), 512, 0, stream>>>(x_bf, Wcat, QKV, nullptr, 8192, 3072, 1024);
  // 16 blocks x 4 waves x 32 q-rows = 2048 q-rows per (h,b)
  attn_kernel<<<dim3(16, 16, 4), 256, 0, stream>>>(QKV, AO);
  // out = AO @ Wo^T + bo : M=8192, N=1024 -> grid 4x32 = 128 blocks (%8==0)
  gemm256<1><<<dim3(4, 32), 512, 0, stream>>>(AO, Wo_bf, out, bo, 8192, 1024, 1024);
}

// Round 7
// 202.397 us; speedup vs baseline: 1.2350x; 1.2350x over previous
//
#include <hip/hip_runtime.h>

// Self-attention, B=4 S=2048 D=1024 H=16 Hd=64, fp32 in/out, bf16 MFMA inside.
// cvt -> GEMM QKV (128^2 tile, BK=64, T2 swizzle, Q*0.125*log2e) -> flash attn
// (32x32 MFMA, in-reg P, swizzled LDS, defer-max, 4 blocks/CU) -> GEMM out+bias.

typedef unsigned short u16;
typedef unsigned int u32;
typedef float f32x4 __attribute__((ext_vector_type(4)));
typedef float f32x16 __attribute__((ext_vector_type(16)));
typedef short s16x8 __attribute__((ext_vector_type(8)));

#define DEVI __device__ __forceinline__

DEVI u16 f32_bf16(float f) {
  unsigned u = __float_as_uint(f);
  return (u16)((u + 0x7FFFu + ((u >> 16) & 1u)) >> 16);
}

DEVI u32 pack_pk(float a, float b) {
  u32 r;
  asm("v_cvt_pk_bf16_f32 %0, %1, %2" : "=v"(r) : "v"(a), "v"(b));
  return r;
}

DEVI void gload_lds16(const void* g, void* l) {
  __builtin_amdgcn_global_load_lds((const __attribute__((address_space(1))) void*)g,
                                   (__attribute__((address_space(3))) void*)l, 16, 0, 0);
}

#if __has_builtin(__builtin_amdgcn_permlane32_swap)
typedef int i32x2 __attribute__((ext_vector_type(2)));
DEVI void plswap(u32& a, u32& b, int hi) {
  i32x2 r = __builtin_amdgcn_permlane32_swap((int)a, (int)b, false, false);
  a = (u32)r[0];
  b = (u32)r[1];
}
#else
DEVI void plswap(u32& a, u32& b, int hi) {
  u32 ta = (u32)__shfl_xor((int)a, 32);
  u32 tb = (u32)__shfl_xor((int)b, 32);
  u32 na = hi ? tb : a;
  u32 nb = hi ? b : ta;
  a = na;
  b = nb;
}
#endif

// ---------------- fp32 -> bf16 conversions ----------------
__global__ void cvt_kernel(const float* __restrict__ in, u16* __restrict__ out, int n4) {
  int i = blockIdx.x * 256 + threadIdx.x;
  if (i >= n4) return;
  float4 v = ((const float4*)in)[i];
  ushort4 o;
  o.x = f32_bf16(v.x); o.y = f32_bf16(v.y);
  o.z = f32_bf16(v.z); o.w = f32_bf16(v.w);
  ((ushort4*)out)[i] = o;
}

__global__ void cvt_w_kernel(const float* __restrict__ wq, const float* __restrict__ wk,
                             const float* __restrict__ wv, const float* __restrict__ wo,
                             u16* __restrict__ wcat, u16* __restrict__ wo_bf) {
  int i = blockIdx.x * 256 + threadIdx.x;
  int m = blockIdx.y;
  const float* src = (m == 0) ? wq : (m == 1) ? wk : (m == 2) ? wv : wo;
  u16* dst = (m < 3) ? (wcat + m * 1048576) : wo_bf;
  float4 v = ((const float4*)src)[i];
  ushort4 o;
  o.x = f32_bf16(v.x); o.y = f32_bf16(v.y);
  o.z = f32_bf16(v.z); o.w = f32_bf16(v.w);
  ((ushort4*)dst)[i] = o;
}

// ---------------- B^T GEMM: C[M,N] = A[M,K] * B[N,K]^T ----------------
// 128x128 tile, BK=64, 256 thr (4 waves, 2x2 of 64x64), swizzled LDS (T2):
// staging via pre-swizzled global source (slot^row&7), frag reads XOR the same.
// MODE 0: bf16 out, cols<1024 scaled by 0.125*log2e. MODE 1: fp32 out + bias.
template <int MODE>
__global__ __launch_bounds__(256, 3) void gemm_bt(
    const u16* __restrict__ A, const u16* __restrict__ B, void* __restrict__ Cout,
    const float* __restrict__ bias, int M, int N, int K) {
  __shared__ u16 As[128 * 64];
  __shared__ u16 Bs[128 * 64];
  const int tid = threadIdx.x;
  const int lane = tid & 63;
  const int w = tid >> 6;
  const int wr = w >> 1, wc = w & 1;
  const int l15 = lane & 15, l4 = lane >> 4;
  const int swz = (l15 & 7) << 3;  // elem-index XOR for frag reads

  // XCD swizzle (nwg % 8 == 0 at both call sites)
  const int gx = gridDim.x;
  const int nwg = gx * gridDim.y;
  int ib = blockIdx.y * gx + blockIdx.x;
  int t = (ib & 7) * (nwg >> 3) + (ib >> 3);
  const int m0 = (t / gx) * 128, n0 = (t % gx) * 128;

  // staging: chunk c = i*256 + w*64 + lane; row = c>>3 (8 slots x 16B per row);
  // linear LDS dest, global slot pre-swizzled: slot_g = (lane&7) ^ (row&7)
  const int srow = w * 8 + (lane >> 3);
  const int scol = ((lane & 7) ^ (lane >> 3)) * 8;

  f32x4 acc[4][4] = {};

  for (int k0 = 0; k0 < K; k0 += 64) {
    __syncthreads();  // previous compute done before LDS overwrite
#pragma unroll
    for (int i = 0; i < 4; ++i) {
      int cb = i * 256 + w * 64;
      int r = i * 32 + srow;
      gload_lds16(A + (size_t)(m0 + r) * K + k0 + scol, &As[cb * 8]);
      gload_lds16(B + (size_t)(n0 + r) * K + k0 + scol, &Bs[cb * 8]);
    }
    __syncthreads();  // drains vmcnt(0) incl. global_load_lds

    s16x8 af[4][2], bf[4][2];
#pragma unroll
    for (int m = 0; m < 4; ++m)
#pragma unroll
      for (int ks = 0; ks < 2; ++ks)
        af[m][ks] = *(const s16x8*)&As[(wr * 64 + m * 16 + l15) * 64 +
                                       ((ks * 32 + l4 * 8) ^ swz)];
#pragma unroll
    for (int n = 0; n < 4; ++n)
#pragma unroll
      for (int ks = 0; ks < 2; ++ks)
        bf[n][ks] = *(const s16x8*)&Bs[(wc * 64 + n * 16 + l15) * 64 +
                                       ((ks * 32 + l4 * 8) ^ swz)];
    __builtin_amdgcn_s_setprio(1);
#pragma unroll
    for (int m = 0; m < 4; ++m)
#pragma unroll
      for (int n = 0; n < 4; ++n)
#pragma unroll
        for (int ks = 0; ks < 2; ++ks)
          acc[m][n] = __builtin_amdgcn_mfma_f32_16x16x32_bf16(af[m][ks], bf[n][ks],
                                                              acc[m][n], 0, 0, 0);
    __builtin_amdgcn_s_setprio(0);
  }

  // epilogue: C/D layout col=lane&15, row=(lane>>4)*4+reg
#pragma unroll
  for (int m = 0; m < 4; ++m) {
    int row = m0 + wr * 64 + m * 16 + l4 * 4;
#pragma unroll
    for (int n = 0; n < 4; ++n) {
      int col = n0 + wc * 64 + n * 16 + l15;
      if (MODE == 0) {
        u16* C = (u16*)Cout;
        float scale = (col < 1024) ? 0.18033688f : 1.0f;  // 0.125 * log2(e)
#pragma unroll
        for (int j = 0; j < 4; ++j)
          C[(size_t)(row + j) * N + col] = f32_bf16(acc[m][n][j] * scale);
      } else {
        float* C = (float*)Cout;
        float bb = bias[col];
#pragma unroll
        for (int j = 0; j < 4; ++j)
          C[(size_t)(row + j) * N + col] = acc[m][n][j] + bb;
      }
    }
  }
}

// ---------------- flash attention, 32x32 MFMA (4 blocks/CU) ----------------
__global__ __launch_bounds__(256, 4) void attn_kernel(const u16* __restrict__ QKV,
                                                      u16* __restrict__ AO) {
  __shared__ u16 Ks[2][64 * 64];  // [key][d], byte ^= (key&7)<<4
  __shared__ u16 Vt[2][64 * 64];  // [d][key], byte ^= (d&7)<<4
  const int tid = threadIdx.x;
  const int lane = tid & 63, w = tid >> 6;
  const int l31 = lane & 31, hi = lane >> 5;

  int ib = blockIdx.z * 256 + blockIdx.y * 16 + blockIdx.x;
  int tb = (ib & 7) * 128 + (ib >> 3);
  const int h = (tb >> 4) & 15, b = tb >> 8;
  const int rowbase = b * 2048;
  const int q0 = (tb & 15) * 128 + w * 32;

  s16x8 qa[4];
  {
    const u16* qp = QKV + (size_t)(rowbase + q0 + l31) * 3072 + h * 64 + hi * 8;
#pragma unroll
    for (int s = 0; s < 4; ++s) qa[s] = *(const s16x8*)(qp + s * 16);
  }

  const char* kbase = (const char*)(QKV + (size_t)rowbase * 3072 + 1024 + h * 64);
  const u16* vbase = QKV + (size_t)rowbase * 3072 + 2048 + h * 64;

  const int kgrow = lane >> 3;
  const int kgcol = ((lane & 7) * 16) ^ ((lane >> 3) << 4);
  const int kv = (tid & 31) * 2;
  const int dv = (tid >> 5) * 8;

  f32x16 o0 = {}, o1 = {};
  float mrow = -1e30f, lrow = 0.f;

  {
#pragma unroll
    for (int c = 0; c < 2; ++c) {
      int chunk = w * 2 + c;
      gload_lds16(kbase + (chunk * 8 + kgrow) * 6144 + kgcol, &Ks[0][chunk * 512]);
    }
    const u16* vp = vbase + kv * 3072 + dv;
    s16x8 v0 = *(const s16x8*)vp, v1 = *(const s16x8*)(vp + 3072);
#pragma unroll
    for (int i = 0; i < 8; ++i) {
      int d = dv + i;
      *(u32*)((char*)&Vt[0][0] + d * 128 + ((kv * 2) ^ ((d & 7) << 4))) =
          (u32)(u16)v0[i] | ((u32)(u16)v1[i] << 16);
    }
  }
  __syncthreads();

  for (int kt = 0; kt < 32; ++kt) {
    const int cur = kt & 1;
    s16x8 v0, v1;
    if (kt < 31) {
      const char* kb = kbase + (size_t)(kt + 1) * 64 * 6144;
#pragma unroll
      for (int c = 0; c < 2; ++c) {
        int chunk = w * 2 + c;
        gload_lds16(kb + (chunk * 8 + kgrow) * 6144 + kgcol, &Ks[cur ^ 1][chunk * 512]);
      }
      const u16* vp = vbase + ((kt + 1) * 64 + kv) * 3072 + dv;
      v0 = *(const s16x8*)vp;
      v1 = *(const s16x8*)(vp + 3072);
    }

    const char* Kb = (const char*)&Ks[cur][0];
    const char* Vb = (const char*)&Vt[cur][0];

    f32x16 sacc[2];
#pragma unroll
    for (int step = 0; step < 2; ++step) {
      const int keyrow = step * 32 + l31;
      const int swzk = (keyrow & 7) << 4;
      f32x16 t = {};
      __builtin_amdgcn_s_setprio(1);
#pragma unroll
      for (int s = 0; s < 4; ++s) {
        s16x8 kf = *(const s16x8*)(Kb + keyrow * 128 + ((s * 32 + hi * 16) ^ swzk));
        t = __builtin_amdgcn_mfma_f32_32x32x16_bf16(kf, qa[s], t, 0, 0, 0);
      }
      __builtin_amdgcn_s_setprio(0);
      sacc[step] = t;
    }

#pragma unroll
    for (int step = 0; step < 2; ++step) {
      f32x16 s_acc = sacc[step];
      float mx[8];
#pragma unroll
      for (int r = 0; r < 8; ++r) mx[r] = fmaxf(s_acc[r], s_acc[r + 8]);
#pragma unroll
      for (int r = 0; r < 4; ++r) mx[r] = fmaxf(mx[r], mx[r + 4]);
      float m4 = fmaxf(fmaxf(mx[0], mx[1]), fmaxf(mx[2], mx[3]));
      m4 = fmaxf(m4, __shfl_xor(m4, 32));
      if (!__all(m4 <= mrow + 8.f)) {  // defer-max (T13)
        float mnew = fmaxf(mrow, m4);
        float corr = __builtin_amdgcn_exp2f(mrow - mnew);
        lrow *= corr;
#pragma unroll
        for (int r = 0; r < 16; ++r) { o0[r] *= corr; o1[r] *= corr; }
        mrow = mnew;
      }
      float p[16];
#pragma unroll
      for (int r = 0; r < 16; ++r) p[r] = __builtin_amdgcn_exp2f(s_acc[r] - mrow);
      float sm[8];
#pragma unroll
      for (int r = 0; r < 8; ++r) sm[r] = p[r] + p[r + 8];
#pragma unroll
      for (int r = 0; r < 4; ++r) sm[r] += sm[r + 4];
      float rs = (sm[0] + sm[1]) + (sm[2] + sm[3]);
      rs += __shfl_xor(rs, 32);
      lrow += rs;

      u32 pk[8];
#pragma unroll
      for (int j = 0; j < 8; ++j) pk[j] = pack_pk(p[2 * j], p[2 * j + 1]);
      plswap(pk[0], pk[2], hi);
      plswap(pk[1], pk[3], hi);
      plswap(pk[4], pk[6], hi);
      plswap(pk[5], pk[7], hi);
      union { u32 u[4]; s16x8 v; } pb0, pb1;
      pb0.u[0] = pk[0]; pb0.u[1] = pk[1]; pb0.u[2] = pk[2]; pb0.u[3] = pk[3];
      pb1.u[0] = pk[4]; pb1.u[1] = pk[5]; pb1.u[2] = pk[6]; pb1.u[3] = pk[7];

      const int swzv = (l31 & 7) << 4;
      __builtin_amdgcn_s_setprio(1);
#pragma unroll
      for (int ks = 0; ks < 2; ++ks) {
        int cbyte = (step * 64 + ks * 32 + hi * 16) ^ swzv;
        s16x8 vf0 = *(const s16x8*)(Vb + l31 * 128 + cbyte);
        s16x8 vf1 = *(const s16x8*)(Vb + (32 + l31) * 128 + cbyte);
        s16x8 pf = ks ? pb1.v : pb0.v;
        o0 = __builtin_amdgcn_mfma_f32_32x32x16_bf16(vf0, pf, o0, 0, 0, 0);
        o1 = __builtin_amdgcn_mfma_f32_32x32x16_bf16(vf1, pf, o1, 0, 0, 0);
      }
      __builtin_amdgcn_s_setprio(0);
    }

    if (kt < 31) {
#pragma unroll
      for (int i = 0; i < 8; ++i) {
        int d = dv + i;
        *(u32*)((char*)&Vt[cur ^ 1][0] + d * 128 + ((kv * 2) ^ ((d & 7) << 4))) =
            (u32)(u16)v0[i] | ((u32)(u16)v1[i] << 16);
      }
    }
    __syncthreads();
  }

  float inv = __builtin_amdgcn_rcpf(lrow);
  u16* op = AO + (size_t)(rowbase + q0 + l31) * 1024 + h * 64;
#pragma unroll
  for (int g = 0; g < 4; ++g) {
    ushort4 s0, s1;
    s0.x = f32_bf16(o0[g * 4 + 0] * inv);
    s0.y = f32_bf16(o0[g * 4 + 1] * inv);
    s0.z = f32_bf16(o0[g * 4 + 2] * inv);
    s0.w = f32_bf16(o0[g * 4 + 3] * inv);
    s1.x = f32_bf16(o1[g * 4 + 0] * inv);
    s1.y = f32_bf16(o1[g * 4 + 1] * inv);
    s1.z = f32_bf16(o1[g * 4 + 2] * inv);
    s1.w = f32_bf16(o1[g * 4 + 3] * inv);
    *(ushort4*)(op + g * 8 + 4 * hi) = s0;
    *(ushort4*)(op + 32 + g * 8 + 4 * hi) = s1;
  }
}

// ---------------- launch ----------------
extern "C" void kernel_launch(void* const* d_in, const int* in_sizes, int n_in,
                              void* d_out, int out_size, void* d_ws, size_t ws_size,
                              hipStream_t stream) {
  const float* x = (const float*)d_in[0];
  const float* Wq = (const float*)d_in[1];
  const float* Wk = (const float*)d_in[2];
  const float* Wv = (const float*)d_in[3];
  const float* Wo = (const float*)d_in[4];
  const float* bo = (const float*)d_in[5];
  float* out = (float*)d_out;

  char* ws = (char*)d_ws;
  u16* x_bf = (u16*)ws;                                   // 16.8 MB
  u16* Wcat = (u16*)(ws + 16777216);                      //  6.3 MB
  u16* Wo_bf = (u16*)(ws + 16777216 + 6291456);           //  2.1 MB
  u16* QKV = (u16*)(ws + 16777216 + 6291456 + 2097152);   // 50.3 MB
  u16* AO = (u16*)(ws + 16777216 + 6291456 + 2097152 + 50331648);  // 16.8 MB

  cvt_kernel<<<8192, 256, 0, stream>>>(x, x_bf, 8192 * 1024 / 4);
  cvt_w_kernel<<<dim3(1024, 4), 256, 0, stream>>>(Wq, Wk, Wv, Wo, Wcat, Wo_bf);

  // QKV = x_bf @ Wcat^T : grid 24x64 = 1536 blocks (%8==0)
  gemm_bt<0><<<dim3(24, 64), 256, 0, stream>>>(x_bf, Wcat, QKV, nullptr, 8192, 3072, 1024);
  // 16 blocks x 4 waves x 32 q-rows = 2048 q-rows per (h,b); 1024 blocks = 4/CU
  attn_kernel<<<dim3(16, 16, 4), 256, 0, stream>>>(QKV, AO);
  // out = AO @ Wo^T + bo : grid 8x64 = 512 blocks (%8==0)
  gemm_bt<1><<<dim3(8, 64), 256, 0, stream>>>(AO, Wo_bf, out, bo, 8192, 1024, 1024);
}